// Round 9
// baseline (1298.022 us; speedup 1.0000x reference)
//
#include <hip/hip_runtime.h>
#include <hip/hip_bf16.h>

typedef __attribute__((ext_vector_type(4))) float floatx4;

#define NN 10000
#define E0 160000
#define ETOT (E0 + NN)
#define IN_DIM 512
#define HID1 1024   /* HEADS*HID = 8*128 */
#define EMB 256

__device__ __forceinline__ float bf2f(unsigned short u) {
    unsigned v = ((unsigned)u) << 16;
    float f;
    __builtin_memcpy(&f, &v, 4);
    return f;
}
__device__ __forceinline__ float loadf(const void* p, size_t i, int isf32) {
    if (isf32) return ((const float*)p)[i];
    return bf2f(((const unsigned short*)p)[i]);
}

// ---------------- zero fill ----------------
__global__ void zero_kernel(int* p, int n) {
    int i = blockIdx.x * 256 + threadIdx.x;
    if (i < n) p[i] = 0;
}

// ---------------- float dtype probe ----------------
__global__ __launch_bounds__(1024) void fdetect_kernel(const unsigned* xw, int* isf32) {
    __shared__ int cnt[1024];
    int t = threadIdx.x;
    int c = 0;
    #pragma unroll
    for (int j = 0; j < 4; ++j) {
        unsigned w = xw[t * 4 + j];
        int ex = (w >> 7) & 0xFF;
        if (ex >= 110 && ex <= 135) c++;
    }
    cnt[t] = c;
    __syncthreads();
    for (int off = 512; off > 0; off >>= 1) {
        if (t < off) cnt[t] += cnt[t + off];
        __syncthreads();
    }
    if (t == 0) *isf32 = (cnt[0] < 2048) ? 1 : 0;
}

// ---------------- edge dtype probe ----------------
__global__ void detect_kernel(const int* ei32, int* flag) {
    int i = blockIdx.x * 256 + threadIdx.x;
    int v = 0;
    int idx = 2 * i + 1;
    if (idx < 2 * E0) v = ei32[idx];
    unsigned long long any = __ballot(v != 0);
    if (any && (threadIdx.x & 63) == 0) atomicOr(flag, 1);
}

__device__ __forceinline__ int load_edge(const void* ei, long long idx, int m32) {
    if (m32) return ((const int*)ei)[idx];
    return (int)(((const long long*)ei)[idx]);
}

// ---------------- CSR build (r4 version, cross-validated vs brute force) ----------------
__global__ void count_kernel(const void* ei, const int* flag, int* counts) {
    int e = blockIdx.x * 256 + threadIdx.x;
    if (e < E0) {
        int m32 = (*flag != 0);
        int d = load_edge(ei, (long long)E0 + e, m32);
        if (d >= 0 && d < NN) atomicAdd(&counts[d], 1);
    }
}

__global__ __launch_bounds__(1024) void scan_kernel(const int* counts, int* offsets, int* cursor) {
    __shared__ int part[1024];
    int t = threadIdx.x;
    int base = t * 10;
    int local[10];
    int s = 0;
    for (int j = 0; j < 10; ++j) {
        int idx = base + j;
        int v = (idx < NN) ? (counts[idx] + 1) : 0;  // +1 self loop
        local[j] = v; s += v;
    }
    part[t] = s;
    __syncthreads();
    for (int off = 1; off < 1024; off <<= 1) {
        int v = (t >= off) ? part[t - off] : 0;
        __syncthreads();
        part[t] += v;
        __syncthreads();
    }
    int run = (t == 0) ? 0 : part[t - 1];
    for (int j = 0; j < 10; ++j) {
        int idx = base + j;
        if (idx < NN) { offsets[idx] = run; cursor[idx] = run; run += local[j]; }
    }
    if (t == 1023) offsets[NN] = part[1023];
}

__global__ void scatter_kernel(const void* ei, const int* flag, int* cursor, int* csr_src) {
    int e = blockIdx.x * 256 + threadIdx.x;
    if (e >= ETOT) return;
    int m32 = (*flag != 0);
    int s, d;
    if (e < E0) { s = load_edge(ei, e, m32); d = load_edge(ei, (long long)E0 + e, m32); }
    else { s = d = e - E0; }
    if (s < 0) s = 0; if (s >= NN) s = NN - 1;
    if (d < 0) d = 0; if (d >= NN) d = NN - 1;
    int pos = atomicAdd(&cursor[d], 1);
    if (pos >= 0 && pos < ETOT) csr_src[pos] = s;
}

// ---------------- simple LDS-tiled VALU GEMM: C[M,N] (fp32) = A[M,K] * B[K,N] ----------------
__global__ __launch_bounds__(256) void gemm_nt(
    const void* __restrict__ A, const void* __restrict__ B,
    float* __restrict__ C, int M, int N, int K,
    int amode, const int* __restrict__ isf32)
{
    int af = (amode >= 0) ? amode : *isf32;
    int bf = *isf32;
    __shared__ float As[16][32];
    __shared__ float Bs[16][33];
    int tx = threadIdx.x & 15, ty = threadIdx.x >> 4;
    int m  = blockIdx.x * 16 + ty;
    int nb = blockIdx.y * 16;
    int n  = nb + tx;
    int mr = (m < M) ? m : (M - 1);
    float acc = 0.f;
    for (int k0 = 0; k0 < K; k0 += 32) {
        As[ty][tx]      = loadf(A, (size_t)mr * K + k0 + tx,      af);
        As[ty][tx + 16] = loadf(A, (size_t)mr * K + k0 + tx + 16, af);
        Bs[ty][tx]      = loadf(B, (size_t)(k0 + tx)      * N + nb + ty, bf);
        Bs[ty][tx + 16] = loadf(B, (size_t)(k0 + tx + 16) * N + nb + ty, bf);
        __syncthreads();
        #pragma unroll
        for (int kk = 0; kk < 32; ++kk) acc += As[ty][kk] * Bs[tx][kk];
        __syncthreads();
    }
    if (m < M) C[(size_t)m * N + n] = acc;
}

// ---------------- alpha for layer 1: as1/ad1 [N,8] ----------------
__global__ __launch_bounds__(256) void alpha1_kernel(
    const float* __restrict__ h1,
    const void* __restrict__ a_src, const void* __restrict__ a_dst,
    const int* __restrict__ isf32,
    float* __restrict__ as1, float* __restrict__ ad1)
{
    int n = blockIdx.x, t = threadIdx.x;
    int f = *isf32;
    floatx4 hv = *(const floatx4*)(const void*)(h1 + (size_t)n * HID1 + t * 4);
    float ps = 0.f, pd = 0.f;
    #pragma unroll
    for (int i = 0; i < 4; ++i) {
        ps += hv[i] * loadf(a_src, t * 4 + i, f);
        pd += hv[i] * loadf(a_dst, t * 4 + i, f);
    }
    __shared__ float rs[256], rdm[256];
    rs[t] = ps; rdm[t] = pd;
    __syncthreads();
    for (int off = 16; off > 0; off >>= 1) {
        if ((t & 31) < off) { rs[t] += rs[t + off]; rdm[t] += rdm[t + off]; }
        __syncthreads();
    }
    if ((t & 31) == 0) {
        int h = t >> 5;
        as1[n * 8 + h] = rs[t];
        ad1[n * 8 + h] = rdm[t];
    }
}

// ---------------- layer-1 softmax + aggregate + ELU -> hmid fp32 ----------------
__global__ __launch_bounds__(256) void agg1_kernel(
    const float* __restrict__ h1, const int* __restrict__ offsets,
    const int* __restrict__ csr_src, const float* __restrict__ as1,
    const float* __restrict__ ad1, const void* __restrict__ b1,
    const int* __restrict__ isf32,
    float* __restrict__ hmid)
{
    int n = blockIdx.x, t = threadIdx.x;
    int f = *isf32;
    int beg = offsets[n], end = offsets[n + 1];
    if (beg < 0) beg = 0; if (end > ETOT) end = ETOT;
    int deg = end - beg; if (deg < 0) deg = 0;
    __shared__ float adsh[8];
    __shared__ float red[8][33];
    __shared__ float m_h[8], rden[8];
    if (t < 8) adsh[t] = ad1[n * 8 + t];
    __syncthreads();

    int ht = t & 7, slot = t >> 3;
    float mx = -1e30f;
    for (int i = slot; i < deg; i += 32) {
        int s = csr_src[beg + i]; s &= 0x7fffffff; if (s >= NN) s = 0;
        float e = as1[s * 8 + ht] + adsh[ht];
        e = e > 0.f ? e : 0.2f * e;
        mx = fmaxf(mx, e);
    }
    red[ht][slot] = mx;
    __syncthreads();
    if (t < 8) {
        float m = -1e30f;
        for (int i = 0; i < 32; ++i) m = fmaxf(m, red[t][i]);
        m_h[t] = m;
    }
    __syncthreads();
    float mh = m_h[ht];
    float sum = 0.f;
    for (int i = slot; i < deg; i += 32) {
        int s = csr_src[beg + i]; s &= 0x7fffffff; if (s >= NN) s = 0;
        float e = as1[s * 8 + ht] + adsh[ht];
        e = e > 0.f ? e : 0.2f * e;
        sum += __expf(e - mh);
    }
    red[ht][slot] = sum;
    __syncthreads();
    if (t < 8) {
        float d = 0.f;
        for (int i = 0; i < 32; ++i) d += red[t][i];
        rden[t] = 1.0f / fmaxf(d, 1e-30f);
    }
    __syncthreads();
    int hc = t >> 5;
    float mh2 = m_h[hc], rd = rden[hc], ad = adsh[hc];
    floatx4 acc = {0, 0, 0, 0};
    for (int i = 0; i < deg; ++i) {
        int s = csr_src[beg + i]; s &= 0x7fffffff; if (s >= NN) s = 0;
        float e = as1[s * 8 + hc] + ad;
        e = e > 0.f ? e : 0.2f * e;
        float w = __expf(e - mh2) * rd;
        floatx4 hv = *(const floatx4*)(const void*)(h1 + (size_t)s * HID1 + t * 4);
        acc += hv * w;
    }
    #pragma unroll
    for (int i = 0; i < 4; ++i) {
        float v = acc[i] + loadf(b1, t * 4 + i, f);
        v = v > 0.f ? v : (__expf(v) - 1.0f);   // ELU
        hmid[(size_t)n * HID1 + t * 4 + i] = v;
    }
}

// ---------------- alpha for layer 2: as2/ad2 [N] ----------------
__global__ __launch_bounds__(256) void alpha2_kernel(
    const float* __restrict__ h2,
    const void* __restrict__ a_src2, const void* __restrict__ a_dst2,
    const int* __restrict__ isf32,
    float* __restrict__ as2, float* __restrict__ ad2)
{
    int n = blockIdx.x, t = threadIdx.x;
    int f = *isf32;
    float v = h2[(size_t)n * EMB + t];
    float ps = v * loadf(a_src2, t, f);
    float pd = v * loadf(a_dst2, t, f);
    __shared__ float rs[256], rdm[256];
    rs[t] = ps; rdm[t] = pd;
    __syncthreads();
    for (int off = 128; off > 0; off >>= 1) {
        if (t < off) { rs[t] += rs[t + off]; rdm[t] += rdm[t + off]; }
        __syncthreads();
    }
    if (t == 0) { as2[n] = rs[0]; ad2[n] = rdm[0]; }
}

// ---------------- layer-2 softmax + aggregate -> out fp32 (ALL nodes) ----------------
__global__ __launch_bounds__(256) void agg2_kernel(
    const float* __restrict__ h2, const int* __restrict__ offsets,
    const int* __restrict__ csr_src, const float* __restrict__ as2,
    const float* __restrict__ ad2, const void* __restrict__ b2,
    const int* __restrict__ isf32,
    float* __restrict__ out)
{
    int n = blockIdx.x, t = threadIdx.x;
    int f = *isf32;
    int beg = offsets[n], end = offsets[n + 1];
    if (beg < 0) beg = 0; if (end > ETOT) end = ETOT;
    int deg = end - beg; if (deg < 0) deg = 0;
    __shared__ float red[256];
    float adn = ad2[n];
    float mx = -1e30f;
    for (int i = t; i < deg; i += 256) {
        int s = csr_src[beg + i]; s &= 0x7fffffff; if (s >= NN) s = 0;
        float e = as2[s] + adn;
        e = e > 0.f ? e : 0.2f * e;
        mx = fmaxf(mx, e);
    }
    red[t] = mx;
    __syncthreads();
    for (int off = 128; off > 0; off >>= 1) {
        if (t < off) red[t] = fmaxf(red[t], red[t + off]);
        __syncthreads();
    }
    float m = red[0];
    __syncthreads();
    float sum = 0.f;
    for (int i = t; i < deg; i += 256) {
        int s = csr_src[beg + i]; s &= 0x7fffffff; if (s >= NN) s = 0;
        float e = as2[s] + adn;
        e = e > 0.f ? e : 0.2f * e;
        sum += __expf(e - m);
    }
    red[t] = sum;
    __syncthreads();
    for (int off = 128; off > 0; off >>= 1) {
        if (t < off) red[t] += red[t + off];
        __syncthreads();
    }
    float rd = 1.0f / fmaxf(red[0], 1e-30f);
    float acc = 0.f;
    for (int i = 0; i < deg; ++i) {
        int s = csr_src[beg + i]; s &= 0x7fffffff; if (s >= NN) s = 0;
        float e = as2[s] + adn;
        e = e > 0.f ? e : 0.2f * e;
        float w = __expf(e - m) * rd;
        acc += w * h2[(size_t)s * EMB + t];
    }
    out[(size_t)n * EMB + t] = acc + loadf(b2, t, f);
}

extern "C" void kernel_launch(void* const* d_in, const int* in_sizes, int n_in,
                              void* d_out, int out_size, void* d_ws, size_t ws_size,
                              hipStream_t stream)
{
    const void* x      = d_in[0];
    const void* edge   = d_in[1];
    const void* W1     = d_in[2];
    const void* a_src1 = d_in[3];
    const void* a_dst1 = d_in[4];
    const void* b1     = d_in[5];
    const void* W2     = d_in[6];
    const void* a_src2 = d_in[7];
    const void* a_dst2 = d_in[8];
    const void* b2     = d_in[9];
    float* out = (float*)d_out;

    char* ws = (char*)d_ws;
    size_t off = 0;
    auto alloc = [&](size_t bytes) -> void* {
        void* p = ws + off;
        off += (bytes + 255) & ~(size_t)255;
        return p;
    };
    int*   counts = (int*)alloc((NN + 2) * 4);   // counts[NN]=eflag, counts[NN+1]=isf32
    int*   offs   = (int*)alloc((NN + 1) * 4);
    int*   cursor = (int*)alloc(NN * 4);
    int*   csr    = (int*)alloc((size_t)ETOT * 4);
    float* as1    = (float*)alloc((size_t)NN * 8 * 4);
    float* ad1    = (float*)alloc((size_t)NN * 8 * 4);
    float* as2    = (float*)alloc((size_t)NN * 4);
    float* ad2    = (float*)alloc((size_t)NN * 4);
    float* hmid   = (float*)alloc((size_t)NN * HID1 * 4);
    float* h1     = (float*)alloc((size_t)NN * HID1 * 4);
    float* h2     = h1;   // h1 dead after agg1; reuse for h2
    int* eflag = counts + NN;
    int* isf32 = counts + NN + 1;

    zero_kernel<<<(NN + 2 + 255) / 256, 256, 0, stream>>>(counts, NN + 2);
    fdetect_kernel<<<1, 1024, 0, stream>>>((const unsigned*)x, isf32);
    detect_kernel<<<(E0 + 255) / 256, 256, 0, stream>>>((const int*)edge, eflag);

    count_kernel<<<(E0 + 255) / 256, 256, 0, stream>>>(edge, eflag, counts);
    scan_kernel<<<1, 1024, 0, stream>>>(counts, offs, cursor);
    scatter_kernel<<<(ETOT + 255) / 256, 256, 0, stream>>>(edge, eflag, cursor, csr);

    // layer 1 GEMM: h1 = x @ W1   [10000,512]x[512,1024]
    dim3 g1(625, HID1 / 16);
    gemm_nt<<<g1, 256, 0, stream>>>(x, W1, h1, NN, HID1, IN_DIM, -1, isf32);

    alpha1_kernel<<<NN, 256, 0, stream>>>(h1, a_src1, a_dst1, isf32, as1, ad1);
    agg1_kernel<<<NN, 256, 0, stream>>>(h1, offs, csr, as1, ad1, b1, isf32, hmid);

    // layer 2 GEMM: h2 = hmid @ W2   [10000,1024]x[1024,256]; A fp32 (amode=1)
    dim3 g2(625, EMB / 16);
    gemm_nt<<<g2, 256, 0, stream>>>(hmid, W2, h2, NN, EMB, HID1, 1, isf32);

    alpha2_kernel<<<NN, 256, 0, stream>>>(h2, a_src2, a_dst2, isf32, as2, ad2);
    agg2_kernel<<<NN, 256, 0, stream>>>(h2, offs, csr, as2, ad2, b2, isf32, out);
}

// Round 10
// 488.499 us; speedup vs baseline: 2.6572x; 2.6572x over previous
//
#include <hip/hip_runtime.h>
#include <hip/hip_bf16.h>

typedef __attribute__((ext_vector_type(8))) short short8;
typedef __attribute__((ext_vector_type(4))) float floatx4;

#define NN 10000
#define E0 160000
#define ETOT (E0 + NN)
#define IN_DIM 512
#define HID1 1024   /* HEADS*HID = 8*128 */
#define EMB 256

__device__ __forceinline__ float bf2f(unsigned short u) {
    unsigned v = ((unsigned)u) << 16;
    float f;
    __builtin_memcpy(&f, &v, 4);
    return f;
}
__device__ __forceinline__ unsigned short f2bf(float f) {
    unsigned u;
    __builtin_memcpy(&u, &f, 4);
    unsigned lsb = (u >> 16) & 1;
    u += 0x7fff + lsb;           // round-to-nearest-even
    return (unsigned short)(u >> 16);
}
__device__ __forceinline__ float loadf(const void* p, size_t i, int isf32) {
    if (isf32) return ((const float*)p)[i];
    return bf2f(((const unsigned short*)p)[i]);
}

// ---------------- zero fill ----------------
__global__ void zero_kernel(int* p, int n) {
    int i = blockIdx.x * 256 + threadIdx.x;
    if (i < n) p[i] = 0;
}

// ---------------- float dtype probe ----------------
__global__ __launch_bounds__(1024) void fdetect_kernel(const unsigned* xw, int* isf32) {
    __shared__ int cnt[1024];
    int t = threadIdx.x;
    int c = 0;
    #pragma unroll
    for (int j = 0; j < 4; ++j) {
        unsigned w = xw[t * 4 + j];
        int ex = (w >> 7) & 0xFF;
        if (ex >= 110 && ex <= 135) c++;
    }
    cnt[t] = c;
    __syncthreads();
    for (int off = 512; off > 0; off >>= 1) {
        if (t < off) cnt[t] += cnt[t + off];
        __syncthreads();
    }
    if (t == 0) *isf32 = (cnt[0] < 2048) ? 1 : 0;
}

// ---------------- edge dtype probe ----------------
__global__ void detect_kernel(const int* ei32, int* flag) {
    int i = blockIdx.x * 256 + threadIdx.x;
    int v = 0;
    int idx = 2 * i + 1;
    if (idx < 2 * E0) v = ei32[idx];
    unsigned long long any = __ballot(v != 0);
    if (any && (threadIdx.x & 63) == 0) atomicOr(flag, 1);
}

__device__ __forceinline__ int load_edge(const void* ei, long long idx, int m32) {
    if (m32) return ((const int*)ei)[idx];
    return (int)(((const long long*)ei)[idx]);
}

// ---------------- CSR build ----------------
__global__ void count_kernel(const void* ei, const int* flag, int* counts) {
    int e = blockIdx.x * 256 + threadIdx.x;
    if (e < E0) {
        int m32 = (*flag != 0);
        int d = load_edge(ei, (long long)E0 + e, m32);
        if (d >= 0 && d < NN) atomicAdd(&counts[d], 1);
    }
}

__global__ __launch_bounds__(1024) void scan_kernel(const int* counts, int* offsets, int* cursor) {
    __shared__ int part[1024];
    int t = threadIdx.x;
    int base = t * 10;
    int local[10];
    int s = 0;
    for (int j = 0; j < 10; ++j) {
        int idx = base + j;
        int v = (idx < NN) ? (counts[idx] + 1) : 0;  // +1 self loop
        local[j] = v; s += v;
    }
    part[t] = s;
    __syncthreads();
    for (int off = 1; off < 1024; off <<= 1) {
        int v = (t >= off) ? part[t - off] : 0;
        __syncthreads();
        part[t] += v;
        __syncthreads();
    }
    int run = (t == 0) ? 0 : part[t - 1];
    for (int j = 0; j < 10; ++j) {
        int idx = base + j;
        if (idx < NN) { offsets[idx] = run; cursor[idx] = run; run += local[j]; }
    }
    if (t == 1023) offsets[NN] = part[1023];
}

__global__ void scatter_kernel(const void* ei, const int* flag, int* cursor, int* csr_src) {
    int e = blockIdx.x * 256 + threadIdx.x;
    if (e >= ETOT) return;
    int m32 = (*flag != 0);
    int s, d;
    if (e < E0) { s = load_edge(ei, e, m32); d = load_edge(ei, (long long)E0 + e, m32); }
    else { s = d = e - E0; }
    if (s < 0) s = 0; if (s >= NN) s = NN - 1;
    if (d < 0) d = 0; if (d >= NN) d = NN - 1;
    int pos = atomicAdd(&cursor[d], 1);
    if (pos >= 0 && pos < ETOT) csr_src[pos] = s;
}

// ---------------- fp32->bf16 conversions ----------------
__global__ void conv_kernel(const void* in, unsigned short* out, int n, const int* isf32) {
    int i = blockIdx.x * 256 + threadIdx.x;
    if (i < n) out[i] = f2bf(loadf(in, i, *isf32));
}

__global__ void convT_kernel(const void* in, unsigned short* out, int R, int C, const int* isf32) {
    int i = blockIdx.x * 256 + threadIdx.x;
    if (i < R * C) {
        int r = i / C, c = i % C;
        out[(size_t)c * R + r] = f2bf(loadf(in, i, *isf32));
    }
}

// ---------------- bf16 MFMA GEMM: C[M,N] (fp32) = A[M,K] * Bt[N,K]^T ----------------
// Fragment layouts per m89/m91-verified mapping: A lane=row(l16), k=quad*8+j;
// C/D col=l16, row=quad*4+reg.
__global__ __launch_bounds__(256) void gemm_bt(
    const unsigned short* __restrict__ A,
    const unsigned short* __restrict__ Bt,
    float* __restrict__ C,
    int M, int N, int K)
{
    int wave = threadIdx.x >> 6;
    int lane = threadIdx.x & 63;
    int quad = lane >> 4;
    int l16  = lane & 15;
    int mblk = blockIdx.x * 64;
    int nblk = blockIdx.y * 64;

    int arow = mblk + wave * 16 + l16;
    if (arow >= M) arow = M - 1;
    const unsigned short* Arow = A + (size_t)arow * K;

    floatx4 acc0 = {0,0,0,0}, acc1 = {0,0,0,0}, acc2 = {0,0,0,0}, acc3 = {0,0,0,0};

    for (int kk = 0; kk < K; kk += 32) {
        int k0 = kk + quad * 8;
        short8 afrag = *(const short8*)(const void*)(Arow + k0);
        short8 b0 = *(const short8*)(const void*)(Bt + (size_t)(nblk +  0 + l16) * K + k0);
        short8 b1 = *(const short8*)(const void*)(Bt + (size_t)(nblk + 16 + l16) * K + k0);
        short8 b2 = *(const short8*)(const void*)(Bt + (size_t)(nblk + 32 + l16) * K + k0);
        short8 b3 = *(const short8*)(const void*)(Bt + (size_t)(nblk + 48 + l16) * K + k0);
        acc0 = __builtin_amdgcn_mfma_f32_16x16x32_bf16(afrag, b0, acc0, 0, 0, 0);
        acc1 = __builtin_amdgcn_mfma_f32_16x16x32_bf16(afrag, b1, acc1, 0, 0, 0);
        acc2 = __builtin_amdgcn_mfma_f32_16x16x32_bf16(afrag, b2, acc2, 0, 0, 0);
        acc3 = __builtin_amdgcn_mfma_f32_16x16x32_bf16(afrag, b3, acc3, 0, 0, 0);
    }

    int crow0 = mblk + wave * 16 + quad * 4;
    int ccol  = nblk + l16;
    #pragma unroll
    for (int r = 0; r < 4; ++r) {
        int row = crow0 + r;
        if (row < M) {
            size_t b = (size_t)row * N + ccol;
            C[b +  0] = acc0[r];
            C[b + 16] = acc1[r];
            C[b + 32] = acc2[r];
            C[b + 48] = acc3[r];
        }
    }
}

// ---------------- alpha for layer 1: as1/ad1 [N,8] ----------------
__global__ __launch_bounds__(256) void alpha1_kernel(
    const float* __restrict__ h1,
    const void* __restrict__ a_src, const void* __restrict__ a_dst,
    const int* __restrict__ isf32,
    float* __restrict__ as1, float* __restrict__ ad1)
{
    int n = blockIdx.x, t = threadIdx.x;
    int f = *isf32;
    floatx4 hv = *(const floatx4*)(const void*)(h1 + (size_t)n * HID1 + t * 4);
    float ps = 0.f, pd = 0.f;
    #pragma unroll
    for (int i = 0; i < 4; ++i) {
        ps += hv[i] * loadf(a_src, t * 4 + i, f);
        pd += hv[i] * loadf(a_dst, t * 4 + i, f);
    }
    __shared__ float rs[256], rdm[256];
    rs[t] = ps; rdm[t] = pd;
    __syncthreads();
    for (int off = 16; off > 0; off >>= 1) {
        if ((t & 31) < off) { rs[t] += rs[t + off]; rdm[t] += rdm[t + off]; }
        __syncthreads();
    }
    if ((t & 31) == 0) {
        int h = t >> 5;
        as1[n * 8 + h] = rs[t];
        ad1[n * 8 + h] = rdm[t];
    }
}

// ---------------- layer-1 softmax + aggregate + ELU -> hmid bf16 ----------------
__global__ __launch_bounds__(256) void agg1_kernel(
    const float* __restrict__ h1, const int* __restrict__ offsets,
    const int* __restrict__ csr_src, const float* __restrict__ as1,
    const float* __restrict__ ad1, const void* __restrict__ b1,
    const int* __restrict__ isf32,
    unsigned short* __restrict__ hmid)
{
    int n = blockIdx.x, t = threadIdx.x;
    int f = *isf32;
    int beg = offsets[n], end = offsets[n + 1];
    if (beg < 0) beg = 0; if (end > ETOT) end = ETOT;
    int deg = end - beg; if (deg < 0) deg = 0;
    __shared__ float adsh[8];
    __shared__ float red[8][33];
    __shared__ float m_h[8], rden[8];
    if (t < 8) adsh[t] = ad1[n * 8 + t];
    __syncthreads();

    int ht = t & 7, slot = t >> 3;
    float mx = -1e30f;
    for (int i = slot; i < deg; i += 32) {
        int s = csr_src[beg + i]; s &= 0x7fffffff; if (s >= NN) s = 0;
        float e = as1[s * 8 + ht] + adsh[ht];
        e = e > 0.f ? e : 0.2f * e;
        mx = fmaxf(mx, e);
    }
    red[ht][slot] = mx;
    __syncthreads();
    if (t < 8) {
        float m = -1e30f;
        for (int i = 0; i < 32; ++i) m = fmaxf(m, red[t][i]);
        m_h[t] = m;
    }
    __syncthreads();
    float mh = m_h[ht];
    float sum = 0.f;
    for (int i = slot; i < deg; i += 32) {
        int s = csr_src[beg + i]; s &= 0x7fffffff; if (s >= NN) s = 0;
        float e = as1[s * 8 + ht] + adsh[ht];
        e = e > 0.f ? e : 0.2f * e;
        sum += __expf(e - mh);
    }
    red[ht][slot] = sum;
    __syncthreads();
    if (t < 8) {
        float d = 0.f;
        for (int i = 0; i < 32; ++i) d += red[t][i];
        rden[t] = 1.0f / fmaxf(d, 1e-30f);
    }
    __syncthreads();
    int hc = t >> 5;
    float mh2 = m_h[hc], rd = rden[hc], ad = adsh[hc];
    floatx4 acc = {0, 0, 0, 0};
    for (int i = 0; i < deg; ++i) {
        int s = csr_src[beg + i]; s &= 0x7fffffff; if (s >= NN) s = 0;
        float e = as1[s * 8 + hc] + ad;
        e = e > 0.f ? e : 0.2f * e;
        float w = __expf(e - mh2) * rd;
        floatx4 hv = *(const floatx4*)(const void*)(h1 + (size_t)s * HID1 + t * 4);
        acc += hv * w;
    }
    #pragma unroll
    for (int i = 0; i < 4; ++i) {
        float v = acc[i] + loadf(b1, t * 4 + i, f);
        v = v > 0.f ? v : (__expf(v) - 1.0f);   // ELU
        hmid[(size_t)n * HID1 + t * 4 + i] = f2bf(v);
    }
}

// ---------------- alpha for layer 2: as2/ad2 [N] ----------------
__global__ __launch_bounds__(256) void alpha2_kernel(
    const float* __restrict__ h2,
    const void* __restrict__ a_src2, const void* __restrict__ a_dst2,
    const int* __restrict__ isf32,
    float* __restrict__ as2, float* __restrict__ ad2)
{
    int n = blockIdx.x, t = threadIdx.x;
    int f = *isf32;
    float v = h2[(size_t)n * EMB + t];
    float ps = v * loadf(a_src2, t, f);
    float pd = v * loadf(a_dst2, t, f);
    __shared__ float rs[256], rdm[256];
    rs[t] = ps; rdm[t] = pd;
    __syncthreads();
    for (int off = 128; off > 0; off >>= 1) {
        if (t < off) { rs[t] += rs[t + off]; rdm[t] += rdm[t + off]; }
        __syncthreads();
    }
    if (t == 0) { as2[n] = rs[0]; ad2[n] = rdm[0]; }
}

// ---------------- layer-2 softmax + aggregate -> out fp32 ----------------
__global__ __launch_bounds__(256) void agg2_kernel(
    const float* __restrict__ h2, const int* __restrict__ offsets,
    const int* __restrict__ csr_src, const float* __restrict__ as2,
    const float* __restrict__ ad2, const void* __restrict__ b2,
    const int* __restrict__ isf32,
    float* __restrict__ out)
{
    int n = blockIdx.x, t = threadIdx.x;
    int f = *isf32;
    int beg = offsets[n], end = offsets[n + 1];
    if (beg < 0) beg = 0; if (end > ETOT) end = ETOT;
    int deg = end - beg; if (deg < 0) deg = 0;
    __shared__ float red[256];
    float adn = ad2[n];
    float mx = -1e30f;
    for (int i = t; i < deg; i += 256) {
        int s = csr_src[beg + i]; s &= 0x7fffffff; if (s >= NN) s = 0;
        float e = as2[s] + adn;
        e = e > 0.f ? e : 0.2f * e;
        mx = fmaxf(mx, e);
    }
    red[t] = mx;
    __syncthreads();
    for (int off = 128; off > 0; off >>= 1) {
        if (t < off) red[t] = fmaxf(red[t], red[t + off]);
        __syncthreads();
    }
    float m = red[0];
    __syncthreads();
    float sum = 0.f;
    for (int i = t; i < deg; i += 256) {
        int s = csr_src[beg + i]; s &= 0x7fffffff; if (s >= NN) s = 0;
        float e = as2[s] + adn;
        e = e > 0.f ? e : 0.2f * e;
        sum += __expf(e - m);
    }
    red[t] = sum;
    __syncthreads();
    for (int off = 128; off > 0; off >>= 1) {
        if (t < off) red[t] += red[t + off];
        __syncthreads();
    }
    float rd = 1.0f / fmaxf(red[0], 1e-30f);
    float acc = 0.f;
    for (int i = 0; i < deg; ++i) {
        int s = csr_src[beg + i]; s &= 0x7fffffff; if (s >= NN) s = 0;
        float e = as2[s] + adn;
        e = e > 0.f ? e : 0.2f * e;
        float w = __expf(e - m) * rd;
        acc += w * h2[(size_t)s * EMB + t];
    }
    out[(size_t)n * EMB + t] = acc + loadf(b2, t, f);
}

extern "C" void kernel_launch(void* const* d_in, const int* in_sizes, int n_in,
                              void* d_out, int out_size, void* d_ws, size_t ws_size,
                              hipStream_t stream)
{
    const void* x      = d_in[0];
    const void* edge   = d_in[1];
    const void* W1     = d_in[2];
    const void* a_src1 = d_in[3];
    const void* a_dst1 = d_in[4];
    const void* b1     = d_in[5];
    const void* W2     = d_in[6];
    const void* a_src2 = d_in[7];
    const void* a_dst2 = d_in[8];
    const void* b2     = d_in[9];
    float* out = (float*)d_out;

    char* ws = (char*)d_ws;
    size_t off = 0;
    auto alloc = [&](size_t bytes) -> void* {
        void* p = ws + off;
        off += (bytes + 255) & ~(size_t)255;
        return p;
    };
    int*            counts = (int*)alloc((NN + 2) * 4);   // counts[NN]=eflag, counts[NN+1]=isf32
    int*            offs   = (int*)alloc((NN + 1) * 4);
    int*            cursor = (int*)alloc(NN * 4);
    int*            csr    = (int*)alloc((size_t)ETOT * 4);
    float*          as1    = (float*)alloc((size_t)NN * 8 * 4);
    float*          ad1    = (float*)alloc((size_t)NN * 8 * 4);
    float*          as2    = (float*)alloc((size_t)NN * 4);
    float*          ad2    = (float*)alloc((size_t)NN * 4);
    unsigned short* xb     = (unsigned short*)alloc((size_t)NN * IN_DIM * 2);
    unsigned short* W1t    = (unsigned short*)alloc((size_t)IN_DIM * HID1 * 2);
    unsigned short* W2t    = (unsigned short*)alloc((size_t)HID1 * EMB * 2);
    unsigned short* hmid   = (unsigned short*)alloc((size_t)NN * HID1 * 2);
    float*          h1     = (float*)alloc((size_t)NN * HID1 * 4);
    float*          h2     = h1;   // h1 dead after agg1; reuse for h2
    int* eflag = counts + NN;
    int* isf32 = counts + NN + 1;

    zero_kernel<<<(NN + 2 + 255) / 256, 256, 0, stream>>>(counts, NN + 2);
    fdetect_kernel<<<1, 1024, 0, stream>>>((const unsigned*)x, isf32);
    detect_kernel<<<(E0 + 255) / 256, 256, 0, stream>>>((const int*)edge, eflag);

    count_kernel<<<(E0 + 255) / 256, 256, 0, stream>>>(edge, eflag, counts);
    scan_kernel<<<1, 1024, 0, stream>>>(counts, offs, cursor);
    scatter_kernel<<<(ETOT + 255) / 256, 256, 0, stream>>>(edge, eflag, cursor, csr);

    // bf16 conversions: x row-major; W1,W2 transposed to [N][K]
    conv_kernel<<<(NN * IN_DIM + 255) / 256, 256, 0, stream>>>(x, xb, NN * IN_DIM, isf32);
    convT_kernel<<<(IN_DIM * HID1 + 255) / 256, 256, 0, stream>>>(W1, W1t, IN_DIM, HID1, isf32);
    convT_kernel<<<(HID1 * EMB + 255) / 256, 256, 0, stream>>>(W2, W2t, HID1, EMB, isf32);

    // layer 1 GEMM (MFMA): h1 = x @ W1   [10000,512]x[512,1024]
    dim3 g1((NN + 63) / 64, HID1 / 64);
    gemm_bt<<<g1, 256, 0, stream>>>(xb, W1t, h1, NN, HID1, IN_DIM);

    alpha1_kernel<<<NN, 256, 0, stream>>>(h1, a_src1, a_dst1, isf32, as1, ad1);
    agg1_kernel<<<NN, 256, 0, stream>>>(h1, offs, csr, as1, ad1, b1, isf32, hmid);

    // layer 2 GEMM (MFMA): h2 = hmid @ W2   [10000,1024]x[1024,256]
    dim3 g2((NN + 63) / 64, EMB / 64);
    gemm_bt<<<g2, 256, 0, stream>>>(hmid, W2t, h2, NN, EMB, HID1);

    alpha2_kernel<<<NN, 256, 0, stream>>>(h2, a_src2, a_dst2, isf32, as2, ad2);
    agg2_kernel<<<NN, 256, 0, stream>>>(h2, offs, csr, as2, ad2, b2, isf32, out);
}

// Round 11
// 456.817 us; speedup vs baseline: 2.8414x; 1.0694x over previous
//
#include <hip/hip_runtime.h>
#include <hip/hip_bf16.h>

typedef __attribute__((ext_vector_type(8))) short short8;
typedef __attribute__((ext_vector_type(4))) float floatx4;
typedef __attribute__((ext_vector_type(4))) unsigned short ushort4v;

#define NN 10000
#define E0 160000
#define ETOT (E0 + NN)
#define IN_DIM 512
#define HID1 1024   /* HEADS*HID = 8*128 */
#define EMB 256

__device__ __forceinline__ float bf2f(unsigned short u) {
    unsigned v = ((unsigned)u) << 16;
    float f;
    __builtin_memcpy(&f, &v, 4);
    return f;
}
__device__ __forceinline__ unsigned short f2bf(float f) {
    unsigned u;
    __builtin_memcpy(&u, &f, 4);
    unsigned lsb = (u >> 16) & 1;
    u += 0x7fff + lsb;           // round-to-nearest-even
    return (unsigned short)(u >> 16);
}
__device__ __forceinline__ float loadf(const void* p, size_t i, int isf32) {
    if (isf32) return ((const float*)p)[i];
    return bf2f(((const unsigned short*)p)[i]);
}

// ---------------- zero fill ----------------
__global__ void zero_kernel(int* p, int n) {
    int i = blockIdx.x * 256 + threadIdx.x;
    if (i < n) p[i] = 0;
}

// ---------------- float dtype probe ----------------
__global__ __launch_bounds__(1024) void fdetect_kernel(const unsigned* xw, int* isf32) {
    __shared__ int cnt[1024];
    int t = threadIdx.x;
    int c = 0;
    #pragma unroll
    for (int j = 0; j < 4; ++j) {
        unsigned w = xw[t * 4 + j];
        int ex = (w >> 7) & 0xFF;
        if (ex >= 110 && ex <= 135) c++;
    }
    cnt[t] = c;
    __syncthreads();
    for (int off = 512; off > 0; off >>= 1) {
        if (t < off) cnt[t] += cnt[t + off];
        __syncthreads();
    }
    if (t == 0) *isf32 = (cnt[0] < 2048) ? 1 : 0;
}

// ---------------- edge dtype probe ----------------
__global__ void detect_kernel(const int* ei32, int* flag) {
    int i = blockIdx.x * 256 + threadIdx.x;
    int v = 0;
    int idx = 2 * i + 1;
    if (idx < 2 * E0) v = ei32[idx];
    unsigned long long any = __ballot(v != 0);
    if (any && (threadIdx.x & 63) == 0) atomicOr(flag, 1);
}

__device__ __forceinline__ int load_edge(const void* ei, long long idx, int m32) {
    if (m32) return ((const int*)ei)[idx];
    return (int)(((const long long*)ei)[idx]);
}

// ---------------- CSR build ----------------
__global__ void count_kernel(const void* ei, const int* flag, int* counts) {
    int e = blockIdx.x * 256 + threadIdx.x;
    if (e < E0) {
        int m32 = (*flag != 0);
        int d = load_edge(ei, (long long)E0 + e, m32);
        if (d >= 0 && d < NN) atomicAdd(&counts[d], 1);
    }
}

__global__ __launch_bounds__(1024) void scan_kernel(const int* counts, int* offsets, int* cursor) {
    __shared__ int part[1024];
    int t = threadIdx.x;
    int base = t * 10;
    int local[10];
    int s = 0;
    for (int j = 0; j < 10; ++j) {
        int idx = base + j;
        int v = (idx < NN) ? (counts[idx] + 1) : 0;  // +1 self loop
        local[j] = v; s += v;
    }
    part[t] = s;
    __syncthreads();
    for (int off = 1; off < 1024; off <<= 1) {
        int v = (t >= off) ? part[t - off] : 0;
        __syncthreads();
        part[t] += v;
        __syncthreads();
    }
    int run = (t == 0) ? 0 : part[t - 1];
    for (int j = 0; j < 10; ++j) {
        int idx = base + j;
        if (idx < NN) { offsets[idx] = run; cursor[idx] = run; run += local[j]; }
    }
    if (t == 1023) offsets[NN] = part[1023];
}

__global__ void scatter_kernel(const void* ei, const int* flag, int* cursor, int* csr_src) {
    int e = blockIdx.x * 256 + threadIdx.x;
    if (e >= ETOT) return;
    int m32 = (*flag != 0);
    int s, d;
    if (e < E0) { s = load_edge(ei, e, m32); d = load_edge(ei, (long long)E0 + e, m32); }
    else { s = d = e - E0; }
    if (s < 0) s = 0; if (s >= NN) s = NN - 1;
    if (d < 0) d = 0; if (d >= NN) d = NN - 1;
    int pos = atomicAdd(&cursor[d], 1);
    if (pos >= 0 && pos < ETOT) csr_src[pos] = s;
}

// ---------------- fp32->bf16 conversions ----------------
__global__ void conv_kernel(const void* in, unsigned short* out, int n, const int* isf32) {
    int i = blockIdx.x * 256 + threadIdx.x;
    if (i < n) out[i] = f2bf(loadf(in, i, *isf32));
}

__global__ void convT_kernel(const void* in, unsigned short* out, int R, int C, const int* isf32) {
    int i = blockIdx.x * 256 + threadIdx.x;
    if (i < R * C) {
        int r = i / C, c = i % C;
        out[(size_t)c * R + r] = f2bf(loadf(in, i, *isf32));
    }
}

// ---------------- bf16 MFMA GEMM: C[M,N] = A[M,K] * Bt[N,K]^T ----------------
// OUTBF16: write bf16 (for h1); else fp32 (for h2).
template<bool OUTBF16>
__global__ __launch_bounds__(256) void gemm_bt(
    const unsigned short* __restrict__ A,
    const unsigned short* __restrict__ Bt,
    void* __restrict__ Cv,
    int M, int N, int K)
{
    int wave = threadIdx.x >> 6;
    int lane = threadIdx.x & 63;
    int quad = lane >> 4;
    int l16  = lane & 15;
    int mblk = blockIdx.x * 64;
    int nblk = blockIdx.y * 64;

    int arow = mblk + wave * 16 + l16;
    if (arow >= M) arow = M - 1;
    const unsigned short* Arow = A + (size_t)arow * K;

    floatx4 acc0 = {0,0,0,0}, acc1 = {0,0,0,0}, acc2 = {0,0,0,0}, acc3 = {0,0,0,0};

    for (int kk = 0; kk < K; kk += 32) {
        int k0 = kk + quad * 8;
        short8 afrag = *(const short8*)(const void*)(Arow + k0);
        short8 b0 = *(const short8*)(const void*)(Bt + (size_t)(nblk +  0 + l16) * K + k0);
        short8 b1 = *(const short8*)(const void*)(Bt + (size_t)(nblk + 16 + l16) * K + k0);
        short8 b2 = *(const short8*)(const void*)(Bt + (size_t)(nblk + 32 + l16) * K + k0);
        short8 b3 = *(const short8*)(const void*)(Bt + (size_t)(nblk + 48 + l16) * K + k0);
        acc0 = __builtin_amdgcn_mfma_f32_16x16x32_bf16(afrag, b0, acc0, 0, 0, 0);
        acc1 = __builtin_amdgcn_mfma_f32_16x16x32_bf16(afrag, b1, acc1, 0, 0, 0);
        acc2 = __builtin_amdgcn_mfma_f32_16x16x32_bf16(afrag, b2, acc2, 0, 0, 0);
        acc3 = __builtin_amdgcn_mfma_f32_16x16x32_bf16(afrag, b3, acc3, 0, 0, 0);
    }

    int crow0 = mblk + wave * 16 + quad * 4;
    int ccol  = nblk + l16;
    #pragma unroll
    for (int r = 0; r < 4; ++r) {
        int row = crow0 + r;
        if (row < M) {
            size_t b = (size_t)row * N + ccol;
            if (OUTBF16) {
                unsigned short* C = (unsigned short*)Cv;
                C[b +  0] = f2bf(acc0[r]);
                C[b + 16] = f2bf(acc1[r]);
                C[b + 32] = f2bf(acc2[r]);
                C[b + 48] = f2bf(acc3[r]);
            } else {
                float* C = (float*)Cv;
                C[b +  0] = acc0[r];
                C[b + 16] = acc1[r];
                C[b + 32] = acc2[r];
                C[b + 48] = acc3[r];
            }
        }
    }
}

// ---------------- alpha for layer 1 (bf16 h1): as1/ad1 [N,8] ----------------
__global__ __launch_bounds__(256) void alpha1_kernel(
    const unsigned short* __restrict__ h1,
    const void* __restrict__ a_src, const void* __restrict__ a_dst,
    const int* __restrict__ isf32,
    float* __restrict__ as1, float* __restrict__ ad1)
{
    int n = blockIdx.x, t = threadIdx.x;
    int f = *isf32;
    ushort4v hv = *(const ushort4v*)(const void*)(h1 + (size_t)n * HID1 + t * 4);
    float ps = 0.f, pd = 0.f;
    #pragma unroll
    for (int i = 0; i < 4; ++i) {
        float h = bf2f(hv[i]);
        ps += h * loadf(a_src, t * 4 + i, f);
        pd += h * loadf(a_dst, t * 4 + i, f);
    }
    __shared__ float rs[256], rdm[256];
    rs[t] = ps; rdm[t] = pd;
    __syncthreads();
    for (int off = 16; off > 0; off >>= 1) {
        if ((t & 31) < off) { rs[t] += rs[t + off]; rdm[t] += rdm[t + off]; }
        __syncthreads();
    }
    if ((t & 31) == 0) {
        int h = t >> 5;
        as1[n * 8 + h] = rs[t];
        ad1[n * 8 + h] = rdm[t];
    }
}

// ---------------- layer-1 softmax + aggregate + ELU (bf16 h1) -> hmid bf16 ----------------
__global__ __launch_bounds__(256) void agg1_kernel(
    const unsigned short* __restrict__ h1, const int* __restrict__ offsets,
    const int* __restrict__ csr_src, const float* __restrict__ as1,
    const float* __restrict__ ad1, const void* __restrict__ b1,
    const int* __restrict__ isf32,
    unsigned short* __restrict__ hmid)
{
    int n = blockIdx.x, t = threadIdx.x;
    int f = *isf32;
    int beg = offsets[n], end = offsets[n + 1];
    if (beg < 0) beg = 0; if (end > ETOT) end = ETOT;
    int deg = end - beg; if (deg < 0) deg = 0;
    __shared__ float adsh[8];
    __shared__ float red[8][33];
    __shared__ float m_h[8], rden[8];
    if (t < 8) adsh[t] = ad1[n * 8 + t];
    __syncthreads();

    int ht = t & 7, slot = t >> 3;
    float mx = -1e30f;
    for (int i = slot; i < deg; i += 32) {
        int s = csr_src[beg + i]; s &= 0x7fffffff; if (s >= NN) s = 0;
        float e = as1[s * 8 + ht] + adsh[ht];
        e = e > 0.f ? e : 0.2f * e;
        mx = fmaxf(mx, e);
    }
    red[ht][slot] = mx;
    __syncthreads();
    if (t < 8) {
        float m = -1e30f;
        for (int i = 0; i < 32; ++i) m = fmaxf(m, red[t][i]);
        m_h[t] = m;
    }
    __syncthreads();
    float mh = m_h[ht];
    float sum = 0.f;
    for (int i = slot; i < deg; i += 32) {
        int s = csr_src[beg + i]; s &= 0x7fffffff; if (s >= NN) s = 0;
        float e = as1[s * 8 + ht] + adsh[ht];
        e = e > 0.f ? e : 0.2f * e;
        sum += __expf(e - mh);
    }
    red[ht][slot] = sum;
    __syncthreads();
    if (t < 8) {
        float d = 0.f;
        for (int i = 0; i < 32; ++i) d += red[t][i];
        rden[t] = 1.0f / fmaxf(d, 1e-30f);
    }
    __syncthreads();
    int hc = t >> 5;
    float mh2 = m_h[hc], rd = rden[hc], ad = adsh[hc];
    floatx4 acc = {0, 0, 0, 0};
    for (int i = 0; i < deg; ++i) {
        int s = csr_src[beg + i]; s &= 0x7fffffff; if (s >= NN) s = 0;
        float e = as1[s * 8 + hc] + ad;
        e = e > 0.f ? e : 0.2f * e;
        float w = __expf(e - mh2) * rd;
        ushort4v hv = *(const ushort4v*)(const void*)(h1 + (size_t)s * HID1 + t * 4);
        #pragma unroll
        for (int j = 0; j < 4; ++j) acc[j] += bf2f(hv[j]) * w;
    }
    #pragma unroll
    for (int i = 0; i < 4; ++i) {
        float v = acc[i] + loadf(b1, t * 4 + i, f);
        v = v > 0.f ? v : (__expf(v) - 1.0f);   // ELU
        hmid[(size_t)n * HID1 + t * 4 + i] = f2bf(v);
    }
}

// ---------------- alpha for layer 2: as2/ad2 [N] ----------------
__global__ __launch_bounds__(256) void alpha2_kernel(
    const float* __restrict__ h2,
    const void* __restrict__ a_src2, const void* __restrict__ a_dst2,
    const int* __restrict__ isf32,
    float* __restrict__ as2, float* __restrict__ ad2)
{
    int n = blockIdx.x, t = threadIdx.x;
    int f = *isf32;
    float v = h2[(size_t)n * EMB + t];
    float ps = v * loadf(a_src2, t, f);
    float pd = v * loadf(a_dst2, t, f);
    __shared__ float rs[256], rdm[256];
    rs[t] = ps; rdm[t] = pd;
    __syncthreads();
    for (int off = 128; off > 0; off >>= 1) {
        if (t < off) { rs[t] += rs[t + off]; rdm[t] += rdm[t + off]; }
        __syncthreads();
    }
    if (t == 0) { as2[n] = rs[0]; ad2[n] = rdm[0]; }
}

// ---------------- layer-2 softmax + aggregate -> out fp32 ----------------
__global__ __launch_bounds__(256) void agg2_kernel(
    const float* __restrict__ h2, const int* __restrict__ offsets,
    const int* __restrict__ csr_src, const float* __restrict__ as2,
    const float* __restrict__ ad2, const void* __restrict__ b2,
    const int* __restrict__ isf32,
    float* __restrict__ out)
{
    int n = blockIdx.x, t = threadIdx.x;
    int f = *isf32;
    int beg = offsets[n], end = offsets[n + 1];
    if (beg < 0) beg = 0; if (end > ETOT) end = ETOT;
    int deg = end - beg; if (deg < 0) deg = 0;
    __shared__ float red[256];
    float adn = ad2[n];
    float mx = -1e30f;
    for (int i = t; i < deg; i += 256) {
        int s = csr_src[beg + i]; s &= 0x7fffffff; if (s >= NN) s = 0;
        float e = as2[s] + adn;
        e = e > 0.f ? e : 0.2f * e;
        mx = fmaxf(mx, e);
    }
    red[t] = mx;
    __syncthreads();
    for (int off = 128; off > 0; off >>= 1) {
        if (t < off) red[t] = fmaxf(red[t], red[t + off]);
        __syncthreads();
    }
    float m = red[0];
    __syncthreads();
    float sum = 0.f;
    for (int i = t; i < deg; i += 256) {
        int s = csr_src[beg + i]; s &= 0x7fffffff; if (s >= NN) s = 0;
        float e = as2[s] + adn;
        e = e > 0.f ? e : 0.2f * e;
        sum += __expf(e - m);
    }
    red[t] = sum;
    __syncthreads();
    for (int off = 128; off > 0; off >>= 1) {
        if (t < off) red[t] += red[t + off];
        __syncthreads();
    }
    float rd = 1.0f / fmaxf(red[0], 1e-30f);
    float acc = 0.f;
    for (int i = 0; i < deg; ++i) {
        int s = csr_src[beg + i]; s &= 0x7fffffff; if (s >= NN) s = 0;
        float e = as2[s] + adn;
        e = e > 0.f ? e : 0.2f * e;
        float w = __expf(e - m) * rd;
        acc += w * h2[(size_t)s * EMB + t];
    }
    out[(size_t)n * EMB + t] = acc + loadf(b2, t, f);
}

extern "C" void kernel_launch(void* const* d_in, const int* in_sizes, int n_in,
                              void* d_out, int out_size, void* d_ws, size_t ws_size,
                              hipStream_t stream)
{
    const void* x      = d_in[0];
    const void* edge   = d_in[1];
    const void* W1     = d_in[2];
    const void* a_src1 = d_in[3];
    const void* a_dst1 = d_in[4];
    const void* b1     = d_in[5];
    const void* W2     = d_in[6];
    const void* a_src2 = d_in[7];
    const void* a_dst2 = d_in[8];
    const void* b2     = d_in[9];
    float* out = (float*)d_out;

    char* ws = (char*)d_ws;
    size_t off = 0;
    auto alloc = [&](size_t bytes) -> void* {
        void* p = ws + off;
        off += (bytes + 255) & ~(size_t)255;
        return p;
    };
    int*            counts = (int*)alloc((NN + 2) * 4);   // counts[NN]=eflag, counts[NN+1]=isf32
    int*            offs   = (int*)alloc((NN + 1) * 4);
    int*            cursor = (int*)alloc(NN * 4);
    int*            csr    = (int*)alloc((size_t)ETOT * 4);
    float*          as1    = (float*)alloc((size_t)NN * 8 * 4);
    float*          ad1    = (float*)alloc((size_t)NN * 8 * 4);
    float*          as2    = (float*)alloc((size_t)NN * 4);
    float*          ad2    = (float*)alloc((size_t)NN * 4);
    unsigned short* xb     = (unsigned short*)alloc((size_t)NN * IN_DIM * 2);
    unsigned short* W1t    = (unsigned short*)alloc((size_t)IN_DIM * HID1 * 2);
    unsigned short* W2t    = (unsigned short*)alloc((size_t)HID1 * EMB * 2);
    unsigned short* h1b    = (unsigned short*)alloc((size_t)NN * HID1 * 2);
    unsigned short* hmid   = (unsigned short*)alloc((size_t)NN * HID1 * 2);
    float*          h2     = (float*)alloc((size_t)NN * EMB * 4);
    int* eflag = counts + NN;
    int* isf32 = counts + NN + 1;

    zero_kernel<<<(NN + 2 + 255) / 256, 256, 0, stream>>>(counts, NN + 2);
    fdetect_kernel<<<1, 1024, 0, stream>>>((const unsigned*)x, isf32);
    detect_kernel<<<(E0 + 255) / 256, 256, 0, stream>>>((const int*)edge, eflag);

    count_kernel<<<(E0 + 255) / 256, 256, 0, stream>>>(edge, eflag, counts);
    scan_kernel<<<1, 1024, 0, stream>>>(counts, offs, cursor);
    scatter_kernel<<<(ETOT + 255) / 256, 256, 0, stream>>>(edge, eflag, cursor, csr);

    // bf16 conversions: x row-major; W1,W2 transposed to [N][K]
    conv_kernel<<<(NN * IN_DIM + 255) / 256, 256, 0, stream>>>(x, xb, NN * IN_DIM, isf32);
    convT_kernel<<<(IN_DIM * HID1 + 255) / 256, 256, 0, stream>>>(W1, W1t, IN_DIM, HID1, isf32);
    convT_kernel<<<(HID1 * EMB + 255) / 256, 256, 0, stream>>>(W2, W2t, HID1, EMB, isf32);

    // layer 1 GEMM (MFMA): h1b (bf16) = x @ W1
    dim3 g1((NN + 63) / 64, HID1 / 64);
    gemm_bt<true><<<g1, 256, 0, stream>>>(xb, W1t, h1b, NN, HID1, IN_DIM);

    alpha1_kernel<<<NN, 256, 0, stream>>>(h1b, a_src1, a_dst1, isf32, as1, ad1);
    agg1_kernel<<<NN, 256, 0, stream>>>(h1b, offs, csr, as1, ad1, b1, isf32, hmid);

    // layer 2 GEMM (MFMA): h2 (fp32) = hmid @ W2
    dim3 g2((NN + 63) / 64, EMB / 64);
    gemm_bt<false><<<g2, 256, 0, stream>>>(hmid, W2t, h2, NN, EMB, HID1);

    alpha2_kernel<<<NN, 256, 0, stream>>>(h2, a_src2, a_dst2, isf32, as2, ad2);
    agg2_kernel<<<NN, 256, 0, stream>>>(h2, offs, csr, as2, ad2, b2, isf32, out);
}

// Round 12
// 359.435 us; speedup vs baseline: 3.6113x; 1.2709x over previous
//
#include <hip/hip_runtime.h>
#include <hip/hip_bf16.h>

typedef __attribute__((ext_vector_type(8))) short short8;
typedef __attribute__((ext_vector_type(4))) float floatx4;
typedef __attribute__((ext_vector_type(4))) unsigned short ushort4v;

#define NN 10000
#define E0 160000
#define ETOT (E0 + NN)
#define IN_DIM 512
#define HID1 1024   /* HEADS*HID = 8*128 */
#define EMB 256
#define MPAD 10112  /* 79 * 128 */
#define LDSS 40     /* LDS row stride (32 + 8 pad) */

__device__ __forceinline__ float bf2f(unsigned short u) {
    unsigned v = ((unsigned)u) << 16;
    float f;
    __builtin_memcpy(&f, &v, 4);
    return f;
}
__device__ __forceinline__ unsigned short f2bf(float f) {
    unsigned u;
    __builtin_memcpy(&u, &f, 4);
    unsigned lsb = (u >> 16) & 1;
    u += 0x7fff + lsb;           // round-to-nearest-even
    return (unsigned short)(u >> 16);
}
__device__ __forceinline__ float loadf(const void* p, size_t i, int isf32) {
    if (isf32) return ((const float*)p)[i];
    return bf2f(((const unsigned short*)p)[i]);
}

// ---------------- zero fill ----------------
__global__ void zero_kernel(int* p, int n) {
    int i = blockIdx.x * 256 + threadIdx.x;
    if (i < n) p[i] = 0;
}

// ---------------- float dtype probe ----------------
__global__ __launch_bounds__(1024) void fdetect_kernel(const unsigned* xw, int* isf32) {
    __shared__ int cnt[1024];
    int t = threadIdx.x;
    int c = 0;
    #pragma unroll
    for (int j = 0; j < 4; ++j) {
        unsigned w = xw[t * 4 + j];
        int ex = (w >> 7) & 0xFF;
        if (ex >= 110 && ex <= 135) c++;
    }
    cnt[t] = c;
    __syncthreads();
    for (int off = 512; off > 0; off >>= 1) {
        if (t < off) cnt[t] += cnt[t + off];
        __syncthreads();
    }
    if (t == 0) *isf32 = (cnt[0] < 2048) ? 1 : 0;
}

// ---------------- edge dtype probe ----------------
__global__ void detect_kernel(const int* ei32, int* flag) {
    int i = blockIdx.x * 256 + threadIdx.x;
    int v = 0;
    int idx = 2 * i + 1;
    if (idx < 2 * E0) v = ei32[idx];
    unsigned long long any = __ballot(v != 0);
    if (any && (threadIdx.x & 63) == 0) atomicOr(flag, 1);
}

__device__ __forceinline__ int load_edge(const void* ei, long long idx, int m32) {
    if (m32) return ((const int*)ei)[idx];
    return (int)(((const long long*)ei)[idx]);
}

// ---------------- CSR build ----------------
__global__ void count_kernel(const void* ei, const int* flag, int* counts) {
    int e = blockIdx.x * 256 + threadIdx.x;
    if (e < E0) {
        int m32 = (*flag != 0);
        int d = load_edge(ei, (long long)E0 + e, m32);
        if (d >= 0 && d < NN) atomicAdd(&counts[d], 1);
    }
}

__global__ __launch_bounds__(1024) void scan_kernel(const int* counts, int* offsets, int* cursor) {
    __shared__ int part[1024];
    int t = threadIdx.x;
    int base = t * 10;
    int local[10];
    int s = 0;
    for (int j = 0; j < 10; ++j) {
        int idx = base + j;
        int v = (idx < NN) ? (counts[idx] + 1) : 0;  // +1 self loop
        local[j] = v; s += v;
    }
    part[t] = s;
    __syncthreads();
    for (int off = 1; off < 1024; off <<= 1) {
        int v = (t >= off) ? part[t - off] : 0;
        __syncthreads();
        part[t] += v;
        __syncthreads();
    }
    int run = (t == 0) ? 0 : part[t - 1];
    for (int j = 0; j < 10; ++j) {
        int idx = base + j;
        if (idx < NN) { offsets[idx] = run; cursor[idx] = run; run += local[j]; }
    }
    if (t == 1023) offsets[NN] = part[1023];
}

__global__ void scatter_kernel(const void* ei, const int* flag, int* cursor, int* csr_src) {
    int e = blockIdx.x * 256 + threadIdx.x;
    if (e >= ETOT) return;
    int m32 = (*flag != 0);
    int s, d;
    if (e < E0) { s = load_edge(ei, e, m32); d = load_edge(ei, (long long)E0 + e, m32); }
    else { s = d = e - E0; }
    if (s < 0) s = 0; if (s >= NN) s = NN - 1;
    if (d < 0) d = 0; if (d >= NN) d = NN - 1;
    int pos = atomicAdd(&cursor[d], 1);
    if (pos >= 0 && pos < ETOT) csr_src[pos] = s;
}

// ---------------- fp32->bf16 conversions ----------------
__global__ void conv_kernel(const void* in, unsigned short* out, int n, const int* isf32) {
    int i = blockIdx.x * 256 + threadIdx.x;
    if (i < n) out[i] = f2bf(loadf(in, i, *isf32));
}

__global__ void convT_kernel(const void* in, unsigned short* out, int R, int C, const int* isf32) {
    int i = blockIdx.x * 256 + threadIdx.x;
    if (i < R * C) {
        int r = i / C, c = i % C;
        out[(size_t)c * R + r] = f2bf(loadf(in, i, *isf32));
    }
}

// ---------------- LDS-tiled bf16 MFMA GEMM: C[Mpad,N] = A[Mpad,K] * Bt[N,K]^T ----------------
// 128x128 tile, BK=32, 4 waves each computing a 64x64 quadrant (4x4 accs).
// Caller guarantees A/C padded to a multiple of 128 rows; N multiple of 128... (gemm2 N=256 ok).
template<bool OUTBF16>
__global__ __launch_bounds__(256) void gemm_tile(
    const unsigned short* __restrict__ A,
    const unsigned short* __restrict__ Bt,
    void* __restrict__ Cv,
    int N, int K)
{
    __shared__ unsigned short As[128 * LDSS];
    __shared__ unsigned short Bs[128 * LDSS];
    int t = threadIdx.x;
    int wave = t >> 6;
    int lane = t & 63;
    int quad = lane >> 4;
    int l16  = lane & 15;
    int mq = wave & 1, nq = wave >> 1;
    size_t mblk = (size_t)blockIdx.x * 128;
    size_t nblk = (size_t)blockIdx.y * 128;

    int srow = t >> 2;            // 0..63 (two rounds: +0, +64)
    int skof = (t & 3) * 8;       // k offset in elements

    floatx4 acc[4][4];
    #pragma unroll
    for (int i = 0; i < 4; ++i)
        #pragma unroll
        for (int j = 0; j < 4; ++j)
            acc[i][j] = (floatx4){0.f, 0.f, 0.f, 0.f};

    const unsigned short* Ab = A + mblk * K + skof;
    const unsigned short* Bb = Bt + nblk * K + skof;

    for (int kk = 0; kk < K; kk += 32) {
        // global loads first (overlap other waves' compute)
        short8 a0 = *(const short8*)(const void*)(Ab + (size_t)srow * K + kk);
        short8 a1 = *(const short8*)(const void*)(Ab + (size_t)(srow + 64) * K + kk);
        short8 b0 = *(const short8*)(const void*)(Bb + (size_t)srow * K + kk);
        short8 b1 = *(const short8*)(const void*)(Bb + (size_t)(srow + 64) * K + kk);
        __syncthreads();   // previous iteration's frag reads done
        *(short8*)(void*)(As + srow * LDSS + skof)        = a0;
        *(short8*)(void*)(As + (srow + 64) * LDSS + skof) = a1;
        *(short8*)(void*)(Bs + srow * LDSS + skof)        = b0;
        *(short8*)(void*)(Bs + (srow + 64) * LDSS + skof) = b1;
        __syncthreads();

        short8 af[4], bf[4];
        #pragma unroll
        for (int i = 0; i < 4; ++i) {
            af[i] = *(const short8*)(const void*)(As + (mq * 64 + i * 16 + l16) * LDSS + quad * 8);
            bf[i] = *(const short8*)(const void*)(Bs + (nq * 64 + i * 16 + l16) * LDSS + quad * 8);
        }
        #pragma unroll
        for (int i = 0; i < 4; ++i)
            #pragma unroll
            for (int j = 0; j < 4; ++j)
                acc[i][j] = __builtin_amdgcn_mfma_f32_16x16x32_bf16(af[i], bf[j], acc[i][j], 0, 0, 0);
    }

    size_t crow0 = mblk + mq * 64 + quad * 4;
    size_t ccol0 = nblk + nq * 64 + l16;
    #pragma unroll
    for (int i = 0; i < 4; ++i) {
        #pragma unroll
        for (int r = 0; r < 4; ++r) {
            size_t row = crow0 + i * 16 + r;
            size_t b = row * N + ccol0;
            #pragma unroll
            for (int j = 0; j < 4; ++j) {
                if (OUTBF16) ((unsigned short*)Cv)[b + j * 16] = f2bf(acc[i][j][r]);
                else         ((float*)Cv)[b + j * 16] = acc[i][j][r];
            }
        }
    }
}

// ---------------- alpha for layer 1 (bf16 h1): as1/ad1 [N,8] ----------------
__global__ __launch_bounds__(256) void alpha1_kernel(
    const unsigned short* __restrict__ h1,
    const void* __restrict__ a_src, const void* __restrict__ a_dst,
    const int* __restrict__ isf32,
    float* __restrict__ as1, float* __restrict__ ad1)
{
    int n = blockIdx.x, t = threadIdx.x;
    int f = *isf32;
    ushort4v hv = *(const ushort4v*)(const void*)(h1 + (size_t)n * HID1 + t * 4);
    float ps = 0.f, pd = 0.f;
    #pragma unroll
    for (int i = 0; i < 4; ++i) {
        float h = bf2f(hv[i]);
        ps += h * loadf(a_src, t * 4 + i, f);
        pd += h * loadf(a_dst, t * 4 + i, f);
    }
    __shared__ float rs[256], rdm[256];
    rs[t] = ps; rdm[t] = pd;
    __syncthreads();
    for (int off = 16; off > 0; off >>= 1) {
        if ((t & 31) < off) { rs[t] += rs[t + off]; rdm[t] += rdm[t + off]; }
        __syncthreads();
    }
    if ((t & 31) == 0) {
        int h = t >> 5;
        as1[n * 8 + h] = rs[t];
        ad1[n * 8 + h] = rdm[t];
    }
}

// ---------------- layer-1 softmax + aggregate + ELU (bf16 h1) -> hmid bf16 ----------------
__global__ __launch_bounds__(256) void agg1_kernel(
    const unsigned short* __restrict__ h1, const int* __restrict__ offsets,
    const int* __restrict__ csr_src, const float* __restrict__ as1,
    const float* __restrict__ ad1, const void* __restrict__ b1,
    const int* __restrict__ isf32,
    unsigned short* __restrict__ hmid)
{
    int n = blockIdx.x, t = threadIdx.x;
    int f = *isf32;
    int beg = offsets[n], end = offsets[n + 1];
    if (beg < 0) beg = 0; if (end > ETOT) end = ETOT;
    int deg = end - beg; if (deg < 0) deg = 0;
    __shared__ float adsh[8];
    __shared__ float red[8][33];
    __shared__ float m_h[8], rden[8];
    if (t < 8) adsh[t] = ad1[n * 8 + t];
    __syncthreads();

    int ht = t & 7, slot = t >> 3;
    float mx = -1e30f;
    for (int i = slot; i < deg; i += 32) {
        int s = csr_src[beg + i]; s &= 0x7fffffff; if (s >= NN) s = 0;
        float e = as1[s * 8 + ht] + adsh[ht];
        e = e > 0.f ? e : 0.2f * e;
        mx = fmaxf(mx, e);
    }
    red[ht][slot] = mx;
    __syncthreads();
    if (t < 8) {
        float m = -1e30f;
        for (int i = 0; i < 32; ++i) m = fmaxf(m, red[t][i]);
        m_h[t] = m;
    }
    __syncthreads();
    float mh = m_h[ht];
    float sum = 0.f;
    for (int i = slot; i < deg; i += 32) {
        int s = csr_src[beg + i]; s &= 0x7fffffff; if (s >= NN) s = 0;
        float e = as1[s * 8 + ht] + adsh[ht];
        e = e > 0.f ? e : 0.2f * e;
        sum += __expf(e - mh);
    }
    red[ht][slot] = sum;
    __syncthreads();
    if (t < 8) {
        float d = 0.f;
        for (int i = 0; i < 32; ++i) d += red[t][i];
        rden[t] = 1.0f / fmaxf(d, 1e-30f);
    }
    __syncthreads();
    int hc = t >> 5;
    float mh2 = m_h[hc], rd = rden[hc], ad = adsh[hc];
    floatx4 acc = {0, 0, 0, 0};
    for (int i = 0; i < deg; ++i) {
        int s = csr_src[beg + i]; s &= 0x7fffffff; if (s >= NN) s = 0;
        float e = as1[s * 8 + hc] + ad;
        e = e > 0.f ? e : 0.2f * e;
        float w = __expf(e - mh2) * rd;
        ushort4v hv = *(const ushort4v*)(const void*)(h1 + (size_t)s * HID1 + t * 4);
        #pragma unroll
        for (int j = 0; j < 4; ++j) acc[j] += bf2f(hv[j]) * w;
    }
    #pragma unroll
    for (int i = 0; i < 4; ++i) {
        float v = acc[i] + loadf(b1, t * 4 + i, f);
        v = v > 0.f ? v : (__expf(v) - 1.0f);   // ELU
        hmid[(size_t)n * HID1 + t * 4 + i] = f2bf(v);
    }
}

// ---------------- alpha for layer 2: as2/ad2 [N] ----------------
__global__ __launch_bounds__(256) void alpha2_kernel(
    const float* __restrict__ h2,
    const void* __restrict__ a_src2, const void* __restrict__ a_dst2,
    const int* __restrict__ isf32,
    float* __restrict__ as2, float* __restrict__ ad2)
{
    int n = blockIdx.x, t = threadIdx.x;
    int f = *isf32;
    float v = h2[(size_t)n * EMB + t];
    float ps = v * loadf(a_src2, t, f);
    float pd = v * loadf(a_dst2, t, f);
    __shared__ float rs[256], rdm[256];
    rs[t] = ps; rdm[t] = pd;
    __syncthreads();
    for (int off = 128; off > 0; off >>= 1) {
        if (t < off) { rs[t] += rs[t + off]; rdm[t] += rdm[t + off]; }
        __syncthreads();
    }
    if (t == 0) { as2[n] = rs[0]; ad2[n] = rdm[0]; }
}

// ---------------- layer-2 softmax + aggregate -> out fp32 ----------------
__global__ __launch_bounds__(256) void agg2_kernel(
    const float* __restrict__ h2, const int* __restrict__ offsets,
    const int* __restrict__ csr_src, const float* __restrict__ as2,
    const float* __restrict__ ad2, const void* __restrict__ b2,
    const int* __restrict__ isf32,
    float* __restrict__ out)
{
    int n = blockIdx.x, t = threadIdx.x;
    int f = *isf32;
    int beg = offsets[n], end = offsets[n + 1];
    if (beg < 0) beg = 0; if (end > ETOT) end = ETOT;
    int deg = end - beg; if (deg < 0) deg = 0;
    __shared__ float red[256];
    float adn = ad2[n];
    float mx = -1e30f;
    for (int i = t; i < deg; i += 256) {
        int s = csr_src[beg + i]; s &= 0x7fffffff; if (s >= NN) s = 0;
        float e = as2[s] + adn;
        e = e > 0.f ? e : 0.2f * e;
        mx = fmaxf(mx, e);
    }
    red[t] = mx;
    __syncthreads();
    for (int off = 128; off > 0; off >>= 1) {
        if (t < off) red[t] = fmaxf(red[t], red[t + off]);
        __syncthreads();
    }
    float m = red[0];
    __syncthreads();
    float sum = 0.f;
    for (int i = t; i < deg; i += 256) {
        int s = csr_src[beg + i]; s &= 0x7fffffff; if (s >= NN) s = 0;
        float e = as2[s] + adn;
        e = e > 0.f ? e : 0.2f * e;
        sum += __expf(e - m);
    }
    red[t] = sum;
    __syncthreads();
    for (int off = 128; off > 0; off >>= 1) {
        if (t < off) red[t] += red[t + off];
        __syncthreads();
    }
    float rd = 1.0f / fmaxf(red[0], 1e-30f);
    float acc = 0.f;
    for (int i = 0; i < deg; ++i) {
        int s = csr_src[beg + i]; s &= 0x7fffffff; if (s >= NN) s = 0;
        float e = as2[s] + adn;
        e = e > 0.f ? e : 0.2f * e;
        float w = __expf(e - m) * rd;
        acc += w * h2[(size_t)s * EMB + t];
    }
    out[(size_t)n * EMB + t] = acc + loadf(b2, t, f);
}

extern "C" void kernel_launch(void* const* d_in, const int* in_sizes, int n_in,
                              void* d_out, int out_size, void* d_ws, size_t ws_size,
                              hipStream_t stream)
{
    const void* x      = d_in[0];
    const void* edge   = d_in[1];
    const void* W1     = d_in[2];
    const void* a_src1 = d_in[3];
    const void* a_dst1 = d_in[4];
    const void* b1     = d_in[5];
    const void* W2     = d_in[6];
    const void* a_src2 = d_in[7];
    const void* a_dst2 = d_in[8];
    const void* b2     = d_in[9];
    float* out = (float*)d_out;

    char* ws = (char*)d_ws;
    size_t off = 0;
    auto alloc = [&](size_t bytes) -> void* {
        void* p = ws + off;
        off += (bytes + 255) & ~(size_t)255;
        return p;
    };
    int*            counts = (int*)alloc((NN + 2) * 4);   // counts[NN]=eflag, counts[NN+1]=isf32
    int*            offs   = (int*)alloc((NN + 1) * 4);
    int*            cursor = (int*)alloc(NN * 4);
    int*            csr    = (int*)alloc((size_t)ETOT * 4);
    float*          as1    = (float*)alloc((size_t)NN * 8 * 4);
    float*          ad1    = (float*)alloc((size_t)NN * 8 * 4);
    float*          as2    = (float*)alloc((size_t)NN * 4);
    float*          ad2    = (float*)alloc((size_t)NN * 4);
    unsigned short* xb     = (unsigned short*)alloc((size_t)MPAD * IN_DIM * 2);
    unsigned short* W1t    = (unsigned short*)alloc((size_t)IN_DIM * HID1 * 2);
    unsigned short* W2t    = (unsigned short*)alloc((size_t)HID1 * EMB * 2);
    unsigned short* h1b    = (unsigned short*)alloc((size_t)MPAD * HID1 * 2);
    unsigned short* hmid   = (unsigned short*)alloc((size_t)MPAD * HID1 * 2);
    float*          h2     = (float*)alloc((size_t)MPAD * EMB * 4);
    int* eflag = counts + NN;
    int* isf32 = counts + NN + 1;

    zero_kernel<<<(NN + 2 + 255) / 256, 256, 0, stream>>>(counts, NN + 2);
    fdetect_kernel<<<1, 1024, 0, stream>>>((const unsigned*)x, isf32);
    detect_kernel<<<(E0 + 255) / 256, 256, 0, stream>>>((const int*)edge, eflag);

    count_kernel<<<(E0 + 255) / 256, 256, 0, stream>>>(edge, eflag, counts);
    scan_kernel<<<1, 1024, 0, stream>>>(counts, offs, cursor);
    scatter_kernel<<<(ETOT + 255) / 256, 256, 0, stream>>>(edge, eflag, cursor, csr);

    // bf16 conversions: x row-major; W1,W2 transposed to [N][K]
    conv_kernel<<<(NN * IN_DIM + 255) / 256, 256, 0, stream>>>(x, xb, NN * IN_DIM, isf32);
    convT_kernel<<<(IN_DIM * HID1 + 255) / 256, 256, 0, stream>>>(W1, W1t, IN_DIM, HID1, isf32);
    convT_kernel<<<(HID1 * EMB + 255) / 256, 256, 0, stream>>>(W2, W2t, HID1, EMB, isf32);

    // layer 1 GEMM (tiled MFMA): h1b (bf16) = x @ W1   [MPAD,512]x[512,1024]
    dim3 g1(MPAD / 128, HID1 / 128);
    gemm_tile<true><<<g1, 256, 0, stream>>>(xb, W1t, h1b, HID1, IN_DIM);

    alpha1_kernel<<<NN, 256, 0, stream>>>(h1b, a_src1, a_dst1, isf32, as1, ad1);
    agg1_kernel<<<NN, 256, 0, stream>>>(h1b, offs, csr, as1, ad1, b1, isf32, hmid);

    // layer 2 GEMM (tiled MFMA): h2 (fp32) = hmid @ W2   [MPAD,1024]x[1024,256]
    dim3 g2(MPAD / 128, EMB / 128);
    gemm_tile<false><<<g2, 256, 0, stream>>>(hmid, W2t, h2, EMB, HID1);

    alpha2_kernel<<<NN, 256, 0, stream>>>(h2, a_src2, a_dst2, isf32, as2, ad2);
    agg2_kernel<<<NN, 256, 0, stream>>>(h2, offs, csr, as2, ad2, b2, isf32, out);
}

// Round 14
// 320.614 us; speedup vs baseline: 4.0486x; 1.1211x over previous
//
#include <hip/hip_runtime.h>
#include <hip/hip_bf16.h>

typedef __attribute__((ext_vector_type(8))) short short8;
typedef __attribute__((ext_vector_type(4))) float floatx4;
typedef __attribute__((ext_vector_type(4))) unsigned short ushort4v;
typedef __attribute__((ext_vector_type(8))) unsigned short ushort8v;

#define NN 10000
#define E0 160000
#define ETOT (E0 + NN)
#define IN_DIM 512
#define HID1 1024   /* HEADS*HID = 8*128 */
#define EMB 256
#define MPAD 10112  /* 79 * 128 */
#define LDSS 40     /* LDS row stride (32 + 8 pad) */

__device__ __forceinline__ float bf2f(unsigned short u) {
    unsigned v = ((unsigned)u) << 16;
    float f;
    __builtin_memcpy(&f, &v, 4);
    return f;
}
__device__ __forceinline__ unsigned short f2bf(float f) {
    unsigned u;
    __builtin_memcpy(&u, &f, 4);
    unsigned lsb = (u >> 16) & 1;
    u += 0x7fff + lsb;           // round-to-nearest-even
    return (unsigned short)(u >> 16);
}
__device__ __forceinline__ float loadf(const void* p, size_t i, int isf32) {
    if (isf32) return ((const float*)p)[i];
    return bf2f(((const unsigned short*)p)[i]);
}

// ---------------- zero fill ----------------
__global__ void zero_kernel(int* p, int n) {
    int i = blockIdx.x * 256 + threadIdx.x;
    if (i < n) p[i] = 0;
}

// ---------------- float dtype probe ----------------
__global__ __launch_bounds__(1024) void fdetect_kernel(const unsigned* xw, int* isf32) {
    __shared__ int cnt[1024];
    int t = threadIdx.x;
    int c = 0;
    #pragma unroll
    for (int j = 0; j < 4; ++j) {
        unsigned w = xw[t * 4 + j];
        int ex = (w >> 7) & 0xFF;
        if (ex >= 110 && ex <= 135) c++;
    }
    cnt[t] = c;
    __syncthreads();
    for (int off = 512; off > 0; off >>= 1) {
        if (t < off) cnt[t] += cnt[t + off];
        __syncthreads();
    }
    if (t == 0) *isf32 = (cnt[0] < 2048) ? 1 : 0;
}

// ---------------- edge dtype probe ----------------
__global__ void detect_kernel(const int* ei32, int* flag) {
    int i = blockIdx.x * 256 + threadIdx.x;
    int v = 0;
    int idx = 2 * i + 1;
    if (idx < 2 * E0) v = ei32[idx];
    unsigned long long any = __ballot(v != 0);
    if (any && (threadIdx.x & 63) == 0) atomicOr(flag, 1);
}

__device__ __forceinline__ int load_edge(const void* ei, long long idx, int m32) {
    if (m32) return ((const int*)ei)[idx];
    return (int)(((const long long*)ei)[idx]);
}

// ---------------- CSR build ----------------
__global__ void count_kernel(const void* ei, const int* flag, int* counts) {
    int e = blockIdx.x * 256 + threadIdx.x;
    if (e < E0) {
        int m32 = (*flag != 0);
        int d = load_edge(ei, (long long)E0 + e, m32);
        if (d >= 0 && d < NN) atomicAdd(&counts[d], 1);
    }
}

__global__ __launch_bounds__(1024) void scan_kernel(const int* counts, int* offsets, int* cursor) {
    __shared__ int part[1024];
    int t = threadIdx.x;
    int base = t * 10;
    int local[10];
    int s = 0;
    for (int j = 0; j < 10; ++j) {
        int idx = base + j;
        int v = (idx < NN) ? (counts[idx] + 1) : 0;  // +1 self loop
        local[j] = v; s += v;
    }
    part[t] = s;
    __syncthreads();
    for (int off = 1; off < 1024; off <<= 1) {
        int v = (t >= off) ? part[t - off] : 0;
        __syncthreads();
        part[t] += v;
        __syncthreads();
    }
    int run = (t == 0) ? 0 : part[t - 1];
    for (int j = 0; j < 10; ++j) {
        int idx = base + j;
        if (idx < NN) { offsets[idx] = run; cursor[idx] = run; run += local[j]; }
    }
    if (t == 1023) offsets[NN] = part[1023];
}

__global__ void scatter_kernel(const void* ei, const int* flag, int* cursor, int* csr_src) {
    int e = blockIdx.x * 256 + threadIdx.x;
    if (e >= ETOT) return;
    int m32 = (*flag != 0);
    int s, d;
    if (e < E0) { s = load_edge(ei, e, m32); d = load_edge(ei, (long long)E0 + e, m32); }
    else { s = d = e - E0; }
    if (s < 0) s = 0; if (s >= NN) s = NN - 1;
    if (d < 0) d = 0; if (d >= NN) d = NN - 1;
    int pos = atomicAdd(&cursor[d], 1);
    if (pos >= 0 && pos < ETOT) csr_src[pos] = s;
}

// ---------------- fp32->bf16 conversions ----------------
__global__ void conv_kernel(const void* in, unsigned short* out, int n, const int* isf32) {
    int i = blockIdx.x * 256 + threadIdx.x;
    if (i < n) out[i] = f2bf(loadf(in, i, *isf32));
}

__global__ void convT_kernel(const void* in, unsigned short* out, int R, int C, const int* isf32) {
    int i = blockIdx.x * 256 + threadIdx.x;
    if (i < R * C) {
        int r = i / C, c = i % C;
        out[(size_t)c * R + r] = f2bf(loadf(in, i, *isf32));
    }
}

// ---------------- LDS-tiled bf16 MFMA GEMM: C[Mpad,N] = A[Mpad,K] * Bt[N,K]^T ----------------
template<bool OUTBF16>
__global__ __launch_bounds__(256) void gemm_tile(
    const unsigned short* __restrict__ A,
    const unsigned short* __restrict__ Bt,
    void* __restrict__ Cv,
    int N, int K)
{
    __shared__ unsigned short As[128 * LDSS];
    __shared__ unsigned short Bs[128 * LDSS];
    int t = threadIdx.x;
    int wave = t >> 6;
    int lane = t & 63;
    int quad = lane >> 4;
    int l16  = lane & 15;
    int mq = wave & 1, nq = wave >> 1;
    size_t mblk = (size_t)blockIdx.x * 128;
    size_t nblk = (size_t)blockIdx.y * 128;

    int srow = t >> 2;
    int skof = (t & 3) * 8;

    floatx4 acc[4][4];
    #pragma unroll
    for (int i = 0; i < 4; ++i)
        #pragma unroll
        for (int j = 0; j < 4; ++j)
            acc[i][j] = (floatx4){0.f, 0.f, 0.f, 0.f};

    const unsigned short* Ab = A + mblk * K + skof;
    const unsigned short* Bb = Bt + nblk * K + skof;

    for (int kk = 0; kk < K; kk += 32) {
        short8 a0 = *(const short8*)(const void*)(Ab + (size_t)srow * K + kk);
        short8 a1 = *(const short8*)(const void*)(Ab + (size_t)(srow + 64) * K + kk);
        short8 b0 = *(const short8*)(const void*)(Bb + (size_t)srow * K + kk);
        short8 b1 = *(const short8*)(const void*)(Bb + (size_t)(srow + 64) * K + kk);
        __syncthreads();
        *(short8*)(void*)(As + srow * LDSS + skof)        = a0;
        *(short8*)(void*)(As + (srow + 64) * LDSS + skof) = a1;
        *(short8*)(void*)(Bs + srow * LDSS + skof)        = b0;
        *(short8*)(void*)(Bs + (srow + 64) * LDSS + skof) = b1;
        __syncthreads();

        short8 af[4], bf[4];
        #pragma unroll
        for (int i = 0; i < 4; ++i) {
            af[i] = *(const short8*)(const void*)(As + (mq * 64 + i * 16 + l16) * LDSS + quad * 8);
            bf[i] = *(const short8*)(const void*)(Bs + (nq * 64 + i * 16 + l16) * LDSS + quad * 8);
        }
        #pragma unroll
        for (int i = 0; i < 4; ++i)
            #pragma unroll
            for (int j = 0; j < 4; ++j)
                acc[i][j] = __builtin_amdgcn_mfma_f32_16x16x32_bf16(af[i], bf[j], acc[i][j], 0, 0, 0);
    }

    size_t crow0 = mblk + mq * 64 + quad * 4;
    size_t ccol0 = nblk + nq * 64 + l16;
    #pragma unroll
    for (int i = 0; i < 4; ++i) {
        #pragma unroll
        for (int r = 0; r < 4; ++r) {
            size_t row = crow0 + i * 16 + r;
            size_t b = row * N + ccol0;
            #pragma unroll
            for (int j = 0; j < 4; ++j) {
                if (OUTBF16) ((unsigned short*)Cv)[b + j * 16] = f2bf(acc[i][j][r]);
                else         ((float*)Cv)[b + j * 16] = acc[i][j][r];
            }
        }
    }
}

// ---------------- alpha for layer 1 (bf16 h1): as1/ad1 [N,8] ----------------
__global__ __launch_bounds__(256) void alpha1_kernel(
    const unsigned short* __restrict__ h1,
    const void* __restrict__ a_src, const void* __restrict__ a_dst,
    const int* __restrict__ isf32,
    float* __restrict__ as1, float* __restrict__ ad1)
{
    int n = blockIdx.x, t = threadIdx.x;
    int f = *isf32;
    ushort4v hv = *(const ushort4v*)(const void*)(h1 + (size_t)n * HID1 + t * 4);
    float ps = 0.f, pd = 0.f;
    #pragma unroll
    for (int i = 0; i < 4; ++i) {
        float h = bf2f(hv[i]);
        ps += h * loadf(a_src, t * 4 + i, f);
        pd += h * loadf(a_dst, t * 4 + i, f);
    }
    __shared__ float rs[256], rdm[256];
    rs[t] = ps; rdm[t] = pd;
    __syncthreads();
    for (int off = 16; off > 0; off >>= 1) {
        if ((t & 31) < off) { rs[t] += rs[t + off]; rdm[t] += rdm[t + off]; }
        __syncthreads();
    }
    if ((t & 31) == 0) {
        int h = t >> 5;
        as1[n * 8 + h] = rs[t];
        ad1[n * 8 + h] = rdm[t];
    }
}

// ---------------- layer-1 single-pass softmax-aggregate + ELU -> hmid bf16 ----------------
// unnormalized accumulation: out = (Σ w_i h_i) / (Σ w_i); w = exp(leaky(e)), e bounded -> no max needed.
// 2 groups x 128 threads; group g handles edges beg+g, beg+g+2, ...; 16B row loads.
__global__ __launch_bounds__(256) void agg1_kernel(
    const unsigned short* __restrict__ h1, const int* __restrict__ offsets,
    const int* __restrict__ csr_src, const float* __restrict__ as1,
    const float* __restrict__ ad1, const void* __restrict__ b1,
    const int* __restrict__ isf32,
    unsigned short* __restrict__ hmid)
{
    int n = blockIdx.x, t = threadIdx.x;
    int f = *isf32;
    int beg = offsets[n], end = offsets[n + 1];
    if (beg < 0) beg = 0; if (end > ETOT) end = ETOT;
    int g = t >> 7;          // edge group 0/1
    int u = t & 127;
    int c0 = u * 8;          // 8 cols per thread
    int hc = u >> 4;         // head = c0/128
    float ad = ad1[n * 8 + hc];

    float den = 0.f;
    float acc[8];
    #pragma unroll
    for (int j = 0; j < 8; ++j) acc[j] = 0.f;

    for (int i = beg + g; i < end; i += 2) {
        int s = csr_src[i]; s &= 0x7fffffff; if (s >= NN) s = 0;
        float e = as1[s * 8 + hc] + ad;
        e = e > 0.f ? e : 0.2f * e;
        float w = __expf(e);
        den += w;
        ushort8v hv = *(const ushort8v*)(const void*)(h1 + (size_t)s * HID1 + c0);
        #pragma unroll
        for (int j = 0; j < 8; ++j) acc[j] += bf2f(hv[j]) * w;
    }

    // combine the two edge groups
    __shared__ float accsh[128][8];
    __shared__ float densh[128];
    if (g == 1) {
        #pragma unroll
        for (int j = 0; j < 8; ++j) accsh[u][j] = acc[j];
        densh[u] = den;
    }
    __syncthreads();
    if (g == 0) {
        den += densh[u];
        float rden = 1.0f / fmaxf(den, 1e-30f);
        ushort8v outw;
        #pragma unroll
        for (int j = 0; j < 8; ++j) {
            float v = (acc[j] + accsh[u][j]) * rden + loadf(b1, c0 + j, f);
            v = v > 0.f ? v : (__expf(v) - 1.0f);   // ELU
            outw[j] = f2bf(v);
        }
        *(ushort8v*)(void*)(hmid + (size_t)n * HID1 + c0) = outw;
    }
}

// ---------------- alpha for layer 2 (bf16 h2): as2/ad2 [N] ----------------
__global__ __launch_bounds__(256) void alpha2_kernel(
    const unsigned short* __restrict__ h2,
    const void* __restrict__ a_src2, const void* __restrict__ a_dst2,
    const int* __restrict__ isf32,
    float* __restrict__ as2, float* __restrict__ ad2)
{
    int n = blockIdx.x, t = threadIdx.x;
    int f = *isf32;
    float v = bf2f(h2[(size_t)n * EMB + t]);
    float ps = v * loadf(a_src2, t, f);
    float pd = v * loadf(a_dst2, t, f);
    __shared__ float rs[256], rdm[256];
    rs[t] = ps; rdm[t] = pd;
    __syncthreads();
    for (int off = 128; off > 0; off >>= 1) {
        if (t < off) { rs[t] += rs[t + off]; rdm[t] += rdm[t + off]; }
        __syncthreads();
    }
    if (t == 0) { as2[n] = rs[0]; ad2[n] = rdm[0]; }
}

// ---------------- layer-2 single-pass softmax-aggregate -> out fp32 ----------------
// 4 groups x 64 threads; 8B bf16 row loads (64*8B = 512B row).
__global__ __launch_bounds__(256) void agg2_kernel(
    const unsigned short* __restrict__ h2, const int* __restrict__ offsets,
    const int* __restrict__ csr_src, const float* __restrict__ as2,
    const float* __restrict__ ad2, const void* __restrict__ b2,
    const int* __restrict__ isf32,
    float* __restrict__ out)
{
    int n = blockIdx.x, t = threadIdx.x;
    int f = *isf32;
    int beg = offsets[n], end = offsets[n + 1];
    if (beg < 0) beg = 0; if (end > ETOT) end = ETOT;
    int g = t >> 6;          // edge group 0..3
    int u = t & 63;
    int c0 = u * 4;          // 4 cols per thread
    float adn = ad2[n];

    float den = 0.f;
    float acc[4];
    #pragma unroll
    for (int j = 0; j < 4; ++j) acc[j] = 0.f;

    for (int i = beg + g; i < end; i += 4) {
        int s = csr_src[i]; s &= 0x7fffffff; if (s >= NN) s = 0;
        float e = as2[s] + adn;
        e = e > 0.f ? e : 0.2f * e;
        float w = __expf(e);
        den += w;
        ushort4v hv = *(const ushort4v*)(const void*)(h2 + (size_t)s * EMB + c0);
        #pragma unroll
        for (int j = 0; j < 4; ++j) acc[j] += bf2f(hv[j]) * w;
    }

    __shared__ float accsh[4][64][4];
    __shared__ float densh[4][64];
    #pragma unroll
    for (int j = 0; j < 4; ++j) accsh[g][u][j] = acc[j];
    densh[g][u] = den;
    __syncthreads();
    if (g == 0) {
        float dtot = densh[0][u] + densh[1][u] + densh[2][u] + densh[3][u];
        float rden = 1.0f / fmaxf(dtot, 1e-30f);
        floatx4 o;
        #pragma unroll
        for (int j = 0; j < 4; ++j) {
            float v = (accsh[0][u][j] + accsh[1][u][j] + accsh[2][u][j] + accsh[3][u][j]) * rden;
            o[j] = v + loadf(b2, c0 + j, f);
        }
        *(floatx4*)(void*)(out + (size_t)n * EMB + c0) = o;
    }
}

extern "C" void kernel_launch(void* const* d_in, const int* in_sizes, int n_in,
                              void* d_out, int out_size, void* d_ws, size_t ws_size,
                              hipStream_t stream)
{
    const void* x      = d_in[0];
    const void* edge   = d_in[1];
    const void* W1     = d_in[2];
    const void* a_src1 = d_in[3];
    const void* a_dst1 = d_in[4];
    const void* b1     = d_in[5];
    const void* W2     = d_in[6];
    const void* a_src2 = d_in[7];
    const void* a_dst2 = d_in[8];
    const void* b2     = d_in[9];
    float* out = (float*)d_out;

    char* ws = (char*)d_ws;
    size_t off = 0;
    auto alloc = [&](size_t bytes) -> void* {
        void* p = ws + off;
        off += (bytes + 255) & ~(size_t)255;
        return p;
    };
    int*            counts = (int*)alloc((NN + 2) * 4);   // counts[NN]=eflag, counts[NN+1]=isf32
    int*            offs   = (int*)alloc((NN + 1) * 4);
    int*            cursor = (int*)alloc(NN * 4);
    int*            csr    = (int*)alloc((size_t)ETOT * 4);
    float*          as1    = (float*)alloc((size_t)NN * 8 * 4);
    float*          ad1    = (float*)alloc((size_t)NN * 8 * 4);
    float*          as2    = (float*)alloc((size_t)NN * 4);
    float*          ad2    = (float*)alloc((size_t)NN * 4);
    unsigned short* xb     = (unsigned short*)alloc((size_t)MPAD * IN_DIM * 2);
    unsigned short* W1t    = (unsigned short*)alloc((size_t)IN_DIM * HID1 * 2);
    unsigned short* W2t    = (unsigned short*)alloc((size_t)HID1 * EMB * 2);
    unsigned short* h1b    = (unsigned short*)alloc((size_t)MPAD * HID1 * 2);
    unsigned short* hmid   = (unsigned short*)alloc((size_t)MPAD * HID1 * 2);
    unsigned short* h2b    = (unsigned short*)alloc((size_t)MPAD * EMB * 2);
    int* eflag = counts + NN;
    int* isf32 = counts + NN + 1;

    zero_kernel<<<(NN + 2 + 255) / 256, 256, 0, stream>>>(counts, NN + 2);
    fdetect_kernel<<<1, 1024, 0, stream>>>((const unsigned*)x, isf32);
    detect_kernel<<<(E0 + 255) / 256, 256, 0, stream>>>((const int*)edge, eflag);

    count_kernel<<<(E0 + 255) / 256, 256, 0, stream>>>(edge, eflag, counts);
    scan_kernel<<<1, 1024, 0, stream>>>(counts, offs, cursor);
    scatter_kernel<<<(ETOT + 255) / 256, 256, 0, stream>>>(edge, eflag, cursor, csr);

    // bf16 conversions: x row-major; W1,W2 transposed to [N][K]
    conv_kernel<<<(NN * IN_DIM + 255) / 256, 256, 0, stream>>>(x, xb, NN * IN_DIM, isf32);
    convT_kernel<<<(IN_DIM * HID1 + 255) / 256, 256, 0, stream>>>(W1, W1t, IN_DIM, HID1, isf32);
    convT_kernel<<<(HID1 * EMB + 255) / 256, 256, 0, stream>>>(W2, W2t, HID1, EMB, isf32);

    // layer 1 GEMM (tiled MFMA): h1b (bf16) = x @ W1
    dim3 g1(MPAD / 128, HID1 / 128);
    gemm_tile<true><<<g1, 256, 0, stream>>>(xb, W1t, h1b, HID1, IN_DIM);

    alpha1_kernel<<<NN, 256, 0, stream>>>(h1b, a_src1, a_dst1, isf32, as1, ad1);
    agg1_kernel<<<NN, 256, 0, stream>>>(h1b, offs, csr, as1, ad1, b1, isf32, hmid);

    // layer 2 GEMM (tiled MFMA): h2b (bf16) = hmid @ W2
    dim3 g2(MPAD / 128, EMB / 128);
    gemm_tile<true><<<g2, 256, 0, stream>>>(hmid, W2t, h2b, EMB, HID1);

    alpha2_kernel<<<NN, 256, 0, stream>>>(h2b, a_src2, a_dst2, isf32, as2, ad2);
    agg2_kernel<<<NN, 256, 0, stream>>>(h2b, offs, csr, as2, ad2, b2, isf32, out);
}